// Round 2
// baseline (121.918 us; speedup 1.0000x reference)
//
#include <hip/hip_runtime.h>

#define BN 16
#define TN 32
#define NCLS 20
#define NBLK 512
#define NTHR 256

// ANCHORS / STRIDES (exact in fp32 — divisions by powers of two)
__constant__ float c_aw[3][3] = {
  {1.25f,  2.0f,   4.125f},
  {1.875f, 3.875f, 3.6875f},
  {3.625f, 4.875f, 11.65625f}
};
__constant__ float c_ah[3][3] = {
  {1.625f,  3.75f,   2.875f},
  {3.8125f, 2.8125f, 7.4375f},
  {2.8125f, 6.1875f, 10.1875f}
};

__device__ __forceinline__ float bce(float x, float t){
  // max(x,0) - x*t + log1p(exp(-|x|))
  return fmaxf(x, 0.0f) - x * t + log1pf(__expf(-fabsf(x)));
}

// Dense base sums over the 5 needed channels (c in [0,5)) of each of the 3
// anchors: those 5 planes are CONTIGUOUS (channels a*25 .. a*25+4), so each
// (b, anchor) pair is one contiguous run of 5*HW floats. float4 index:
//   v = run*(5*HW4) + off,  addr4 = 25*HW4*run + off,  c = off / HW4
template<int HW4>
__device__ __forceinline__ void base_sum(const float* __restrict__ p, int lb, int nb,
                                         int tid, float* acc){
  const int total = BN * 15 * HW4;           // 5 channels * 3 anchors * B, in float4
  for (int v = lb * NTHR + tid; v < total; v += nb * NTHR){
    const int run = v / (5 * HW4);           // compile-time divisor -> magic mul
    const int off = v - run * (5 * HW4);
    const int c4  = off / HW4;
    const float4 x = ((const float4*)p)[(size_t)(25 * HW4) * run + off];
    if (c4 < 4) acc[0] += x.x*x.x + x.y*x.y + x.z*x.z + x.w*x.w;
    else        acc[1] += bce(x.x,0.f) + bce(x.y,0.f) + bce(x.z,0.f) + bce(x.w,0.f);
  }
}

// ws layout (floats, zeroed by memset before launch):
//   [l*8+0] box_corr  [l*8+1] obj_corr  [l*8+2] noobj_sub
//   [l*8+3] cls_corr  [l*8+4] count     [l*8+5] box_base  [l*8+6] noobj_base
//   [24] done-counter (int)

__global__ __launch_bounds__(NTHR)
void k_fused(const float* __restrict__ p0, const float* __restrict__ p1,
             const float* __restrict__ p2, const float* __restrict__ tg,
             float* __restrict__ ws, float* __restrict__ out){
  const int bid = blockIdx.x;
  const int tid = threadIdx.x;

  __shared__ int   lin_s[NTHR];
  __shared__ float red[NTHR];
  __shared__ bool  is_last;

  // ---- phase 1: sparse target corrections (blocks 0..5; 48 groups of 32) ----
  float tvals[5] = {0.f, 0.f, 0.f, 0.f, 0.f};
  int tlevel = 0;
  if (bid < 6){
    const int g = bid * 8 + (tid >> 5);     // group = level*16 + b, uniform level per block
    tlevel      = g >> 4;
    const int b = g & 15;
    const int t = tid & 31;
    const float* p = (tlevel == 0) ? p0 : (tlevel == 1 ? p1 : p2);
    const int Hh   = (tlevel == 0) ? 80 : (tlevel == 1 ? 40 : 20);
    const int HW   = Hh * Hh;

    const float cls_f = tg[(b*TN + t)*5 + 0];
    const float tx    = tg[(b*TN + t)*5 + 1];
    const float ty    = tg[(b*TN + t)*5 + 2];
    const float tw    = tg[(b*TN + t)*5 + 3];
    const float th    = tg[(b*TN + t)*5 + 4];

    int gx = (int)floorf(tx * (float)Hh); gx = min(max(gx, 0), Hh - 1);
    int gy = (int)floorf(ty * (float)Hh); gy = min(max(gy, 0), Hh - 1);

    float best = -1.0f; int ba = 0;
    for (int a = 0; a < 3; ++a){
      float aw = c_aw[tlevel][a], ah = c_ah[tlevel][a];
      float inter = fminf(tw, aw) * fminf(th, ah);
      float iou = inter / (tw*th + aw*ah - inter + 1e-6f);
      if (iou > best){ best = iou; ba = a; }   // first-max wins == jnp.argmax
    }
    const bool valid_pre = best > 0.3f;
    const int  lin = (gy * Hh + gx) * 3 + ba;

    lin_s[tid] = valid_pre ? lin : -1;
    __syncthreads();
    bool valid = valid_pre;
    if (valid_pre){
      const int gbase = tid & ~31;
      for (int u = t + 1; u < TN; ++u)
        if (lin_s[gbase + u] == lin){ valid = false; break; }  // shadowed by later target
    }

    if (valid){
      const float baw = c_aw[tlevel][ba], bah = c_ah[tlevel][ba];
      float tb[4];
      tb[0] = tx * (float)Hh - (float)gx;
      tb[1] = ty * (float)Hh - (float)gy;
      tb[2] = logf(tw / baw + 1e-6f);
      tb[3] = logf(th / bah + 1e-6f);
      const int cls = (int)cls_f;
      const size_t base = (size_t)(b*75 + ba*25) * HW + (size_t)(gy * Hh + gx);
      float box_corr = 0.f;
      for (int c = 0; c < 4; ++c){
        float x = p[base + (size_t)c * HW];
        float d = x - tb[c];
        box_corr += d*d - x*x;
      }
      float x4 = p[base + (size_t)4 * HW];
      float cls_corr = 0.f;
      for (int c = 0; c < NCLS; ++c){
        float x = p[base + (size_t)(5 + c) * HW];
        cls_corr += bce(x, (c == cls) ? 1.0f : 0.0f);
      }
      tvals[0] = box_corr;
      tvals[1] = bce(x4, 1.0f);
      tvals[2] = bce(x4, 0.0f);
      tvals[3] = cls_corr;
      tvals[4] = 1.0f;
    }
  }

  // ---- phase 2: dense base sums (all 512 blocks, statically partitioned) ----
  float bacc[2] = {0.f, 0.f};
  int blevel;
  if (bid < 390)      { blevel = 0; base_sum<1600>(p0, bid,       390, tid, bacc); }
  else if (bid < 488) { blevel = 1; base_sum< 400>(p1, bid - 390,  98, tid, bacc); }
  else                { blevel = 2; base_sum< 100>(p2, bid - 488,  24, tid, bacc); }

  // ---- block reductions + atomic accumulate ----
  float sums[7];
  int nred = (bid < 6) ? 7 : 2;
  for (int m = 0; m < nred; ++m){
    float v = (m < 2) ? bacc[m] : tvals[m - 2];
    __syncthreads();
    red[tid] = v;
    __syncthreads();
    for (int s = NTHR/2; s > 0; s >>= 1){
      if (tid < s) red[tid] += red[tid + s];
      __syncthreads();
    }
    sums[m] = red[0];
  }

  if (tid == 0){
    atomicAdd(&ws[blevel*8 + 5], sums[0]);
    atomicAdd(&ws[blevel*8 + 6], sums[1]);
    if (bid < 6)
      for (int m = 0; m < 5; ++m)
        atomicAdd(&ws[tlevel*8 + m], sums[m + 2]);
    __threadfence();
    int old = atomicAdd((int*)(ws + 24), 1);
    is_last = (old == NBLK - 1);
  }
  __syncthreads();

  // ---- final combine by the last-done block ----
  if (is_last && tid == 0){
    float f[24];
    for (int i = 0; i < 24; ++i) f[i] = atomicAdd(&ws[i], 0.0f);  // coherent read
    const float cells[3] = {307200.f, 76800.f, 19200.f};          // B*H*W*3
    float total = 0.f;
    for (int l = 0; l < 3; ++l){
      float Sbox  = f[l*8 + 5] + f[l*8 + 0];
      float obj   = f[l*8 + 1];
      float noobj = f[l*8 + 6] - f[l*8 + 2];
      float clsl  = f[l*8 + 3];
      float cnt   = f[l*8 + 4];
      float n_obj   = cnt + 1e-6f;
      float n_noobj = (cells[l] - cnt) + 1e-6f;
      total += 0.05f * Sbox / n_obj
             + 1.5f  * (obj / n_obj + 0.5f * noobj / n_noobj)
             + 0.15f * clsl / n_obj;
    }
    out[0] = total;
  }
}

extern "C" void kernel_launch(void* const* d_in, const int* in_sizes, int n_in,
                              void* d_out, int out_size, void* d_ws, size_t ws_size,
                              hipStream_t stream) {
  const float* p0 = (const float*)d_in[0];
  const float* p1 = (const float*)d_in[1];
  const float* p2 = (const float*)d_in[2];
  const float* tg = (const float*)d_in[3];
  float* out = (float*)d_out;
  float* ws  = (float*)d_ws;

  hipMemsetAsync(ws, 0, 128, stream);   // zero accumulators + done counter
  k_fused<<<NBLK, NTHR, 0, stream>>>(p0, p1, p2, tg, ws, out);
}

// Round 3
// 96.931 us; speedup vs baseline: 1.2578x; 1.2578x over previous
//
#include <hip/hip_runtime.h>

#define BN 16
#define TN 32
#define NCLS 20
#define NBLK 512
#define NTHR 256

// ANCHORS / STRIDES (exact in fp32 — divisions by powers of two)
__constant__ float c_aw[3][3] = {
  {1.25f,  2.0f,   4.125f},
  {1.875f, 3.875f, 3.6875f},
  {3.625f, 4.875f, 11.65625f}
};
__constant__ float c_ah[3][3] = {
  {1.625f,  3.75f,   2.875f},
  {3.8125f, 2.8125f, 7.4375f},
  {2.8125f, 6.1875f, 10.1875f}
};

__device__ __forceinline__ float bce(float x, float t){
  // max(x,0) - x*t + log1p(exp(-|x|))
  return fmaxf(x, 0.0f) - x * t + log1pf(__expf(-fabsf(x)));
}

// ws float layout (no zeroing required — every slot written unconditionally):
//   [64   + bid*2 + m]  k_base partials, bid in [0,512), m=0 box, m=1 noobj
//   [2048 + g*8  + m]   k_targets partials, g = level*16+b in [0,48), m in [0,5)
//                       m: 0 box_corr, 1 obj, 2 noobj_sub, 3 cls, 4 count

// ---------------- k_targets: one wave per (level, batch) group ----------------
__global__ __launch_bounds__(64)
void k_targets(const float* __restrict__ p0, const float* __restrict__ p1,
               const float* __restrict__ p2, const float* __restrict__ tg,
               float* __restrict__ ws){
  const int g      = blockIdx.x;        // 0..47
  const int tlevel = g >> 4;
  const int b      = g & 15;
  const int lane   = threadIdx.x;       // 0..63
  const int t      = (lane < 32) ? lane : 31;   // clamp: lanes 32-63 shadow t=31 (results discarded)

  const float* p = (tlevel == 0) ? p0 : (tlevel == 1 ? p1 : p2);
  const int Hh   = (tlevel == 0) ? 80 : (tlevel == 1 ? 40 : 20);
  const int HW   = Hh * Hh;

  __shared__ int lin_s[32];

  const float cls_f = tg[(b*TN + t)*5 + 0];
  const float tx    = tg[(b*TN + t)*5 + 1];
  const float ty    = tg[(b*TN + t)*5 + 2];
  const float tw    = tg[(b*TN + t)*5 + 3];
  const float th    = tg[(b*TN + t)*5 + 4];

  int gx = (int)floorf(tx * (float)Hh); gx = min(max(gx, 0), Hh - 1);
  int gy = (int)floorf(ty * (float)Hh); gy = min(max(gy, 0), Hh - 1);

  float best = -1.0f; int ba = 0;
  #pragma unroll
  for (int a = 0; a < 3; ++a){
    float aw = c_aw[tlevel][a], ah = c_ah[tlevel][a];
    float inter = fminf(tw, aw) * fminf(th, ah);
    float iou = inter / (tw*th + aw*ah - inter + 1e-6f);
    if (iou > best){ best = iou; ba = a; }   // first-max wins == jnp.argmax
  }
  const bool valid_pre = best > 0.3f;
  const int  lin = (gy * Hh + gx) * 3 + ba;

  if (lane < 32) lin_s[lane] = valid_pre ? lin : -1;
  __syncthreads();

  bool valid = (lane < 32) && valid_pre;
  if (valid){
    for (int u = t + 1; u < TN; ++u)
      if (lin_s[u] == lin){ valid = false; break; }   // shadowed by later target
  }

  // Gather all 25 channel values unconditionally (addresses always in-bounds:
  // gx/gy clamped, ba in [0,3)) so loads issue back-to-back — one waitcnt.
  const size_t base = (size_t)(b*75 + ba*25) * HW + (size_t)(gy * Hh + gx);
  float xs[25];
  #pragma unroll
  for (int c = 0; c < 25; ++c) xs[c] = p[base + (size_t)c * HW];

  float v0 = 0.f, v1 = 0.f, v2 = 0.f, v3 = 0.f, v4 = 0.f;
  if (valid){
    const float baw = c_aw[tlevel][ba], bah = c_ah[tlevel][ba];
    float tb0 = tx * (float)Hh - (float)gx;
    float tb1 = ty * (float)Hh - (float)gy;
    float tb2 = logf(tw / baw + 1e-6f);
    float tb3 = logf(th / bah + 1e-6f);
    float d0 = xs[0]-tb0, d1 = xs[1]-tb1, d2 = xs[2]-tb2, d3 = xs[3]-tb3;
    v0 = (d0*d0 - xs[0]*xs[0]) + (d1*d1 - xs[1]*xs[1])
       + (d2*d2 - xs[2]*xs[2]) + (d3*d3 - xs[3]*xs[3]);
    v1 = bce(xs[4], 1.0f);
    v2 = bce(xs[4], 0.0f);
    const int cls = (int)cls_f;
    float cc = 0.f;
    #pragma unroll
    for (int c = 0; c < NCLS; ++c)
      cc += bce(xs[5 + c], (c == cls) ? 1.0f : 0.0f);
    v3 = cc;
    v4 = 1.0f;
  }

  // full-wave shuffle reduction (inactive lanes contribute 0)
  #pragma unroll
  for (int off = 32; off > 0; off >>= 1){
    v0 += __shfl_down(v0, off, 64);
    v1 += __shfl_down(v1, off, 64);
    v2 += __shfl_down(v2, off, 64);
    v3 += __shfl_down(v3, off, 64);
    v4 += __shfl_down(v4, off, 64);
  }
  if (lane == 0){
    float* o = ws + 2048 + g*8;
    o[0] = v0; o[1] = v1; o[2] = v2; o[3] = v3; o[4] = v4;
  }
}

// ---------------- k_base: dense sums over the 5 needed channels ----------------
// The 5 needed channels (c in [0,5)) of each anchor are contiguous planes
// (channels a*25 .. a*25+4): each (b, anchor) is one run of 5*HW floats.
template<int HW4>
__device__ __forceinline__ void base_sum(const float* __restrict__ p, int lb, int nb,
                                         int tid, float& a0, float& a1){
  const int total = BN * 15 * HW4;           // in float4
  for (int v = lb * NTHR + tid; v < total; v += nb * NTHR){
    const int run = v / (5 * HW4);           // compile-time divisor -> magic mul
    const int off = v - run * (5 * HW4);
    const int c4  = off / HW4;
    const float4 x = ((const float4*)p)[(size_t)(25 * HW4) * run + off];
    if (c4 < 4) a0 += x.x*x.x + x.y*x.y + x.z*x.z + x.w*x.w;
    else        a1 += bce(x.x,0.f) + bce(x.y,0.f) + bce(x.z,0.f) + bce(x.w,0.f);
  }
}

__global__ __launch_bounds__(NTHR)
void k_base(const float* __restrict__ p0, const float* __restrict__ p1,
            const float* __restrict__ p2, float* __restrict__ ws){
  const int bid = blockIdx.x, tid = threadIdx.x;
  float a0 = 0.f, a1 = 0.f;
  if (bid < 390)      base_sum<1600>(p0, bid,       390, tid, a0, a1);
  else if (bid < 488) base_sum< 400>(p1, bid - 390,  98, tid, a0, a1);
  else                base_sum< 100>(p2, bid - 488,  24, tid, a0, a1);

  // wave shuffle reduce, then tiny LDS cross-wave combine (1 barrier)
  #pragma unroll
  for (int off = 32; off > 0; off >>= 1){
    a0 += __shfl_down(a0, off, 64);
    a1 += __shfl_down(a1, off, 64);
  }
  __shared__ float sm[8];
  const int wid = tid >> 6;
  if ((tid & 63) == 0){ sm[wid*2] = a0; sm[wid*2+1] = a1; }
  __syncthreads();
  if (tid == 0){
    ws[64 + bid*2 + 0] = sm[0] + sm[2] + sm[4] + sm[6];
    ws[64 + bid*2 + 1] = sm[1] + sm[3] + sm[5] + sm[7];
  }
}

// ---------------- k_final: combine everything ----------------
__global__ __launch_bounds__(256)
void k_final(const float* __restrict__ ws, float* __restrict__ out){
  __shared__ float sb[6];    // per-level base sums (box, noobj)
  __shared__ float st[24];   // per-level target sums
  const int tid = threadIdx.x;
  if (tid < 6)  sb[tid] = 0.f;
  if (tid < 24) st[tid] = 0.f;
  __syncthreads();

  for (int j = tid; j < NBLK; j += 256){
    const int lv = (j < 390) ? 0 : ((j < 488) ? 1 : 2);
    atomicAdd(&sb[lv*2 + 0], ws[64 + 2*j + 0]);
    atomicAdd(&sb[lv*2 + 1], ws[64 + 2*j + 1]);
  }
  if (tid < 48){
    const int tl = tid >> 4;
    #pragma unroll
    for (int m = 0; m < 5; ++m)
      atomicAdd(&st[tl*8 + m], ws[2048 + tid*8 + m]);
  }
  __syncthreads();

  if (tid == 0){
    const float cells[3] = {307200.f, 76800.f, 19200.f};   // B*H*W*3
    float total = 0.f;
    for (int l = 0; l < 3; ++l){
      float Sbox  = sb[l*2 + 0] + st[l*8 + 0];
      float obj   = st[l*8 + 1];
      float noobj = sb[l*2 + 1] - st[l*8 + 2];
      float clsl  = st[l*8 + 3];
      float cnt   = st[l*8 + 4];
      float n_obj   = cnt + 1e-6f;
      float n_noobj = (cells[l] - cnt) + 1e-6f;
      total += 0.05f * Sbox / n_obj
             + 1.5f  * (obj / n_obj + 0.5f * noobj / n_noobj)
             + 0.15f * clsl / n_obj;
    }
    out[0] = total;
  }
}

extern "C" void kernel_launch(void* const* d_in, const int* in_sizes, int n_in,
                              void* d_out, int out_size, void* d_ws, size_t ws_size,
                              hipStream_t stream) {
  const float* p0 = (const float*)d_in[0];
  const float* p1 = (const float*)d_in[1];
  const float* p2 = (const float*)d_in[2];
  const float* tg = (const float*)d_in[3];
  float* out = (float*)d_out;
  float* ws  = (float*)d_ws;   // uses < 16 KB

  k_targets<<<48,   64,   0, stream>>>(p0, p1, p2, tg, ws);
  k_base   <<<NBLK, NTHR, 0, stream>>>(p0, p1, p2, ws);
  k_final  <<<1,    256,  0, stream>>>(ws, out);
}

// Round 4
// 90.093 us; speedup vs baseline: 1.3533x; 1.0759x over previous
//
#include <hip/hip_runtime.h>

#define BN 16
#define TN 32
#define NCLS 20
#define NBASE 512
#define NTHR 256

// ANCHORS / STRIDES (exact in fp32 — divisions by powers of two)
__constant__ float c_aw[3][3] = {
  {1.25f,  2.0f,   4.125f},
  {1.875f, 3.875f, 3.6875f},
  {3.625f, 4.875f, 11.65625f}
};
__constant__ float c_ah[3][3] = {
  {1.625f,  3.75f,   2.875f},
  {3.8125f, 2.8125f, 7.4375f},
  {2.8125f, 6.1875f, 10.1875f}
};

__device__ __forceinline__ float bce(float x, float t){
  // precise: max(x,0) - x*t + log1p(exp(-|x|))  (used only for ~48 targets)
  return fmaxf(x, 0.0f) - x * t + log1pf(__expf(-fabsf(x)));
}

__device__ __forceinline__ float softplus_fast(float x){
  // bce(x, 0) = max(x,0) + log(1 + exp(-|x|)); fast log/exp, err ~1e-7 abs
  return fmaxf(x, 0.0f) + __logf(1.0f + __expf(-fabsf(x)));
}

// ws float layout (no zeroing required — every slot written unconditionally):
//   [64   + j*2 + m]    base partials, j in [0,512), m=0 box, m=1 noobj
//   [2048 + g*8 + m]    target partials, g = level*16+b in [0,48), m in [0,5)
//                       m: 0 box_corr, 1 obj, 2 noobj_sub, 3 cls, 4 count

// Dense base sums: the 5 needed channels (c in [0,5)) of each anchor are
// contiguous planes (channels a*25 .. a*25+4) -> each (b, anchor) is one
// contiguous run of 5*HW floats.
template<int HW4>
__device__ __forceinline__ void base_sum(const float* __restrict__ p, int lb, int nb,
                                         int tid, float& a0, float& a1){
  const int total = BN * 15 * HW4;           // in float4
  for (int v = lb * NTHR + tid; v < total; v += nb * NTHR){
    const int run = v / (5 * HW4);           // compile-time divisor -> magic mul
    const int off = v - run * (5 * HW4);
    const int c4  = off / HW4;
    const float4 x = ((const float4*)p)[(size_t)(25 * HW4) * run + off];
    if (c4 < 4) a0 += x.x*x.x + x.y*x.y + x.z*x.z + x.w*x.w;
    else        a1 += softplus_fast(x.x) + softplus_fast(x.y)
                    + softplus_fast(x.z) + softplus_fast(x.w);
  }
}

__global__ __launch_bounds__(NTHR)
void k_main(const float* __restrict__ p0, const float* __restrict__ p1,
            const float* __restrict__ p2, const float* __restrict__ tg,
            float* __restrict__ ws){
  const int bid = blockIdx.x;
  const int tid = threadIdx.x;

  if (bid < 48){
    // -------- target block: wave 0 only, no barriers, no LDS --------
    if (tid >= 64) return;
    const int g      = bid;
    const int tlevel = g >> 4;
    const int b      = g & 15;
    const int lane   = tid;                       // 0..63
    const int t      = (lane < 32) ? lane : 31;   // lanes 32-63: clones, discarded

    const float* p = (tlevel == 0) ? p0 : (tlevel == 1 ? p1 : p2);
    const int Hh   = (tlevel == 0) ? 80 : (tlevel == 1 ? 40 : 20);
    const int HW   = Hh * Hh;

    const float cls_f = tg[(b*TN + t)*5 + 0];
    const float tx    = tg[(b*TN + t)*5 + 1];
    const float ty    = tg[(b*TN + t)*5 + 2];
    const float tw    = tg[(b*TN + t)*5 + 3];
    const float th    = tg[(b*TN + t)*5 + 4];

    int gx = (int)floorf(tx * (float)Hh); gx = min(max(gx, 0), Hh - 1);
    int gy = (int)floorf(ty * (float)Hh); gy = min(max(gy, 0), Hh - 1);

    float best = -1.0f; int ba = 0;
    #pragma unroll
    for (int a = 0; a < 3; ++a){
      float aw = c_aw[tlevel][a], ah = c_ah[tlevel][a];
      float inter = fminf(tw, aw) * fminf(th, ah);
      float iou = inter / (tw*th + aw*ah - inter + 1e-6f);
      if (iou > best){ best = iou; ba = a; }   // first-max wins == jnp.argmax
    }
    const bool valid_pre = best > 0.3f;
    const int  lin = (gy * Hh + gx) * 3 + ba;

    // shadow check via wave shuffles: lin_v[u] == -1 encodes !valid_pre[u]
    int lin_v = (valid_pre && lane < 32) ? lin : -1;
    bool valid = valid_pre && (lane < 32);
    #pragma unroll 1
    for (int u = 1; u < TN; ++u){
      int other = __shfl(lin_v, u, 64);        // lin of later target u
      if (valid && u > t && other == lin) valid = false;
    }

    // gather all 25 channel values unconditionally (addresses always in-bounds)
    const size_t base = (size_t)(b*75 + ba*25) * HW + (size_t)(gy * Hh + gx);
    float xs[25];
    #pragma unroll
    for (int c = 0; c < 25; ++c) xs[c] = p[base + (size_t)c * HW];

    float v0 = 0.f, v1 = 0.f, v2 = 0.f, v3 = 0.f, v4 = 0.f;
    if (valid){
      const float baw = c_aw[tlevel][ba], bah = c_ah[tlevel][ba];
      float tb0 = tx * (float)Hh - (float)gx;
      float tb1 = ty * (float)Hh - (float)gy;
      float tb2 = logf(tw / baw + 1e-6f);
      float tb3 = logf(th / bah + 1e-6f);
      float d0 = xs[0]-tb0, d1 = xs[1]-tb1, d2 = xs[2]-tb2, d3 = xs[3]-tb3;
      v0 = (d0*d0 - xs[0]*xs[0]) + (d1*d1 - xs[1]*xs[1])
         + (d2*d2 - xs[2]*xs[2]) + (d3*d3 - xs[3]*xs[3]);
      v1 = bce(xs[4], 1.0f);
      v2 = bce(xs[4], 0.0f);
      const int cls = (int)cls_f;
      float cc = 0.f;
      #pragma unroll
      for (int c = 0; c < NCLS; ++c)
        cc += bce(xs[5 + c], (c == cls) ? 1.0f : 0.0f);
      v3 = cc;
      v4 = 1.0f;
    }

    #pragma unroll
    for (int off = 32; off > 0; off >>= 1){
      v0 += __shfl_down(v0, off, 64);
      v1 += __shfl_down(v1, off, 64);
      v2 += __shfl_down(v2, off, 64);
      v3 += __shfl_down(v3, off, 64);
      v4 += __shfl_down(v4, off, 64);
    }
    if (lane == 0){
      float* o = ws + 2048 + g*8;
      o[0] = v0; o[1] = v1; o[2] = v2; o[3] = v3; o[4] = v4;
    }
    return;
  }

  // -------- base block --------
  const int j = bid - 48;                  // 0..511
  float a0 = 0.f, a1 = 0.f;
  if (j < 390)      base_sum<1600>(p0, j,       390, tid, a0, a1);
  else if (j < 488) base_sum< 400>(p1, j - 390,  98, tid, a0, a1);
  else              base_sum< 100>(p2, j - 488,  24, tid, a0, a1);

  #pragma unroll
  for (int off = 32; off > 0; off >>= 1){
    a0 += __shfl_down(a0, off, 64);
    a1 += __shfl_down(a1, off, 64);
  }
  __shared__ float sm[8];
  const int wid = tid >> 6;
  if ((tid & 63) == 0){ sm[wid*2] = a0; sm[wid*2+1] = a1; }
  __syncthreads();
  if (tid == 0){
    ws[64 + j*2 + 0] = sm[0] + sm[2] + sm[4] + sm[6];
    ws[64 + j*2 + 1] = sm[1] + sm[3] + sm[5] + sm[7];
  }
}

__global__ __launch_bounds__(256)
void k_final(const float* __restrict__ ws, float* __restrict__ out){
  __shared__ float sb[6];    // per-level base sums (box, noobj)
  __shared__ float st[24];   // per-level target sums
  const int tid = threadIdx.x;
  if (tid < 6)  sb[tid] = 0.f;
  if (tid < 24) st[tid] = 0.f;
  __syncthreads();

  for (int j = tid; j < NBASE; j += 256){
    const int lv = (j < 390) ? 0 : ((j < 488) ? 1 : 2);
    atomicAdd(&sb[lv*2 + 0], ws[64 + 2*j + 0]);
    atomicAdd(&sb[lv*2 + 1], ws[64 + 2*j + 1]);
  }
  if (tid < 48){
    const int tl = tid >> 4;
    #pragma unroll
    for (int m = 0; m < 5; ++m)
      atomicAdd(&st[tl*8 + m], ws[2048 + tid*8 + m]);
  }
  __syncthreads();

  if (tid == 0){
    const float cells[3] = {307200.f, 76800.f, 19200.f};   // B*H*W*3
    float total = 0.f;
    for (int l = 0; l < 3; ++l){
      float Sbox  = sb[l*2 + 0] + st[l*8 + 0];
      float obj   = st[l*8 + 1];
      float noobj = sb[l*2 + 1] - st[l*8 + 2];
      float clsl  = st[l*8 + 3];
      float cnt   = st[l*8 + 4];
      float n_obj   = cnt + 1e-6f;
      float n_noobj = (cells[l] - cnt) + 1e-6f;
      total += 0.05f * Sbox / n_obj
             + 1.5f  * (obj / n_obj + 0.5f * noobj / n_noobj)
             + 0.15f * clsl / n_obj;
    }
    out[0] = total;
  }
}

extern "C" void kernel_launch(void* const* d_in, const int* in_sizes, int n_in,
                              void* d_out, int out_size, void* d_ws, size_t ws_size,
                              hipStream_t stream) {
  const float* p0 = (const float*)d_in[0];
  const float* p1 = (const float*)d_in[1];
  const float* p2 = (const float*)d_in[2];
  const float* tg = (const float*)d_in[3];
  float* out = (float*)d_out;
  float* ws  = (float*)d_ws;   // uses < 16 KB

  k_main <<<48 + NBASE, NTHR, 0, stream>>>(p0, p1, p2, tg, ws);
  k_final<<<1,          256,  0, stream>>>(ws, out);
}